// Round 10
// baseline (176.217 us; speedup 1.0000x reference)
//
#include <hip/hip_runtime.h>
#include <hip/hip_bf16.h>

typedef unsigned short u16;
typedef unsigned int   u32;
typedef __attribute__((ext_vector_type(8)))  short bf16x8;
typedef __attribute__((ext_vector_type(16))) float f32x16;

#define GPB 4
#define ZERO16 (f32x16){0.f,0.f,0.f,0.f,0.f,0.f,0.f,0.f,0.f,0.f,0.f,0.f,0.f,0.f,0.f,0.f}
#define MFMA32 __builtin_amdgcn_mfma_f32_32x32x16_bf16

__constant__ int ADJ_DEG[16] = {3,4,4,3, 4,5,5,4, 4,5,5,4, 3,4,4,3};
__constant__ int ADJ_SRC[16][5] = {
  {0,1,4,0,0},   {1,0,2,5,0},   {2,1,3,6,0},   {3,2,7,0,0},
  {4,5,0,8,0},   {5,4,6,1,9},   {6,5,7,2,10},  {7,6,3,11,0},
  {8,9,4,12,0},  {9,8,10,5,13}, {10,9,11,6,14},{11,10,7,15,0},
  {12,13,8,0,0}, {13,12,14,9,0},{14,13,15,10,0},{15,14,11,0,0}
};

struct SMem {
  char hA[64*512];      // bf16 [64 rows][256 cols] row-major, XOR-swizzled
  char hBT[4*256*32];   // bf16 X^T [g][c][node 0..15], 32B rows, XOR swizzled
  union {
    struct { float asd[64][8]; char ptb[16*16*32]; } post;              // 2KB + 8KB (per g,h,d)
    struct { float grs[4][64]; float z1[4][128]; float red[2][8][2]; } mlp;
  } u;
};  // ~74 KB -> 2 blocks/CU

__device__ __forceinline__ int swz(int row, int b) {
  return (row << 9) + (b ^ ((row & 7) << 4) ^ (((row >> 3) & 1) << 5));
}
__device__ __forceinline__ int xswz(int g, int c, int b) {
  return (g << 13) + (c << 5) + (b ^ (((c >> 2) & 1) << 4) ^ (((c >> 3) & 1) << 3));
}
__device__ __forceinline__ int ptbx(int g, int h, int d, int b) {   // b in {0,16}
  return (((g*4 + h)*16 + d) << 5) + (b ^ (((h ^ (d >> 2)) & 1) << 4));
}
__device__ __forceinline__ u32 f2bf1(float x) {
  u32 u = __float_as_uint(x);
  return (u + 0x7fffu + ((u >> 16) & 1u)) >> 16;
}
__device__ __forceinline__ u32 pk2(float a, float b) {
  __hip_bfloat162 h2 = __float22bfloat162_rn(make_float2(a, b));
  union { __hip_bfloat162 h; u32 u; } cv; cv.h = h2; return cv.u;
}
__device__ __forceinline__ bf16x8 hbt_read(const SMem& sm, int g, int c, int hi) {
  union { uint2 u2[2]; bf16x8 v; } cv;
  cv.u2[0] = *(const uint2*)(sm.hBT + xswz(g, c, hi*16));
  cv.u2[1] = *(const uint2*)(sm.hBT + xswz(g, c, hi*16 + 8));
  return cv.v;
}

// ---- GEMM x = h @ W via 32x32x16; wave w owns n-tile w (32 cols), both m-halves.
// Waves 0-1 also compute fused att tile (nt=8) for m-half w, then wave-local softmax -> ptb.
template<int KS>
__device__ __forceinline__ void gemm32(SMem& sm, const uint4* __restrict__ wsrc, int t) {
  const int lane = t & 63, w = t >> 6;
  const int l31 = lane & 31, hi = lane >> 5;
  const bool hasAtt = (w < 2);

  f32x16 acc0 = ZERO16, acc1 = ZERO16, accA = ZERO16;

  // software-pipelined W-fragment loads (L2 latency hides under MFMA)
  uint4 bw = wsrc[w*64 + lane];
  uint4 ba;
  if (hasAtt) ba = wsrc[8*64 + lane];

#pragma unroll
  for (int ks = 0; ks < KS; ++ks) {
    uint4 bwn, ban;
    if (ks + 1 < KS) {
      bwn = wsrc[((ks+1)*9 + w)*64 + lane];
      if (hasAtt) ban = wsrc[((ks+1)*9 + 8)*64 + lane];
    }
    const bf16x8 a0 = *(const bf16x8*)(sm.hA + swz(l31,      ks*32 + hi*16));
    const bf16x8 a1 = *(const bf16x8*)(sm.hA + swz(32 + l31, ks*32 + hi*16));
    acc0 = MFMA32(a0, *(const bf16x8*)&bw, acc0, 0, 0, 0);
    acc1 = MFMA32(a1, *(const bf16x8*)&bw, acc1, 0, 0, 0);
    if (hasAtt) accA = MFMA32((w == 0) ? a0 : a1, *(const bf16x8*)&ba, accA, 0, 0, 0);
    if (ks + 1 < KS) { bw = bwn; if (hasAtt) ba = ban; }
  }

  // X^T epilogue: lane = col c, rows r = (reg&3)+8*(reg>>2)+4*hi
  const int c = w*32 + l31;
#pragma unroll
  for (int mh = 0; mh < 2; ++mh) {
    const f32x16 A = mh ? acc1 : acc0;
#pragma unroll
    for (int grp = 0; grp < 4; ++grp) {
      const int g  = mh*2 + (grp >> 1);
      const int n0 = (grp & 1)*8 + hi*4;
      uint2 o;
      o.x = pk2(A[grp*4+0], A[grp*4+1]);
      o.y = pk2(A[grp*4+2], A[grp*4+3]);
      *(uint2*)(sm.hBT + xswz(g, c, n0*2)) = o;
    }
  }

  if (hasAtt) {
    if (l31 < 8) {
#pragma unroll
      for (int grp = 0; grp < 4; ++grp) {
        const int g  = w*2 + (grp >> 1);
        const int n0 = (grp & 1)*8 + hi*4;
#pragma unroll
        for (int i = 0; i < 4; ++i)
          sm.u.post.asd[g*16 + n0 + i][l31] = accA[grp*4+i];
      }
    }
    // wave-local softmax (same-wave LDS ops are in-order; no block barrier needed)
    const int g = w*2 + hi;
    const int h = lane & 3;
#pragma unroll
    for (int dd = 0; dd < 2; ++dd) {
      const int d = ((lane >> 2) & 7) + dd*8;
      const int deg = ADJ_DEG[d];
      const float advl = sm.u.post.asd[g*16 + d][4 + h];
      float al[5]; int srcs[5];
      float m = -1e30f;
#pragma unroll
      for (int k = 0; k < 5; ++k) {
        srcs[k] = (k < deg) ? ADJ_SRC[d][k] : 99;
        float v = 0.f;
        if (k < deg) {
          v = sm.u.post.asd[g*16 + srcs[k]][h] + advl;
          v = (v > 0.f) ? v : 0.2f * v;          // leaky_relu 0.2
          m = fmaxf(m, v);
        }
        al[k] = v;
      }
      float ssum = 0.f;
#pragma unroll
      for (int k = 0; k < 5; ++k)
        if (k < deg) { const float e = __expf(al[k] - m); al[k] = e; ssum += e; }
      const float inv = 1.f / ssum;
      float p[16];
#pragma unroll
      for (int s = 0; s < 16; ++s) {
        float v = 0.f;
#pragma unroll
        for (int k = 0; k < 5; ++k) v = (srcs[k] == s) ? al[k] * inv : v;
        p[s] = v;
      }
      uint4 lo, hh;
      lo.x = pk2(p[0],p[1]);   lo.y = pk2(p[2],p[3]);   lo.z = pk2(p[4],p[5]);   lo.w = pk2(p[6],p[7]);
      hh.x = pk2(p[8],p[9]);   hh.y = pk2(p[10],p[11]); hh.z = pk2(p[12],p[13]); hh.w = pk2(p[14],p[15]);
      *(uint4*)(sm.u.post.ptb + ptbx(g, h, d, 0))  = lo;   // logical s 0-7
      *(uint4*)(sm.u.post.ptb + ptbx(g, h, d, 16)) = hh;   // logical s 8-15
    }
  }
}

// ---- aggregation: D = X^T @ P_h^T via 32x32x16 ----
template<int MODE>   // 0: concat+bias+relu -> hA; 1: mean heads+nodes + bias -> grs directly
__device__ __forceinline__ void agg32(SMem& sm, const float* __restrict__ bias, int t) {
  const int lane = t & 63, w = t >> 6;
  const int l31 = lane & 31, hi = lane >> 5;
  const int g = w >> 1;
  const bf16x8 zero8 = {0,0,0,0,0,0,0,0};

  if (MODE == 0) {
#pragma unroll
    for (int i = 0; i < 4; ++i) {
      const int mt = (w & 1)*4 + i;
      const int h = mt >> 1;                      // head owning this 32-col feature tile
      bf16x8 pb = zero8;
      if (l31 < 16)
        pb = *(const bf16x8*)(sm.u.post.ptb + ptbx(g, h, l31, hi*16));
      const bf16x8 a = hbt_read(sm, g, mt*32 + l31, hi);
      f32x16 acc = ZERO16;
      acc = MFMA32(a, pb, acc, 0, 0, 0);
      if (l31 < 16) {
        const int row = g*16 + l31;
#pragma unroll
        for (int grp = 0; grp < 4; ++grp) {
          const int cb = mt*32 + grp*8 + hi*4;
          const float4 bv = *(const float4*)(bias + cb);
          uint2 o;
          o.x = pk2(fmaxf(acc[grp*4+0] + bv.x, 0.f), fmaxf(acc[grp*4+1] + bv.y, 0.f));
          o.y = pk2(fmaxf(acc[grp*4+2] + bv.z, 0.f), fmaxf(acc[grp*4+3] + bv.w, 0.f));
          *(uint2*)(sm.hA + swz(row, 2*cb)) = o;
        }
      }
    }
  } else {
    const int mt = w & 1;
    f32x16 acc = ZERO16;
#pragma unroll
    for (int h = 0; h < 4; ++h) {                 // chain heads with per-head P
      bf16x8 pb = zero8;
      if (l31 < 16)
        pb = *(const bf16x8*)(sm.u.post.ptb + ptbx(g, h, l31, hi*16));
      const bf16x8 a = hbt_read(sm, g, h*64 + mt*32 + l31, hi);
      acc = MFMA32(a, pb, acc, 0, 0, 0);
    }
    // sum over dst nodes (cols = lanes l31 0..15; 16..31 hold zeros) via shuffles,
    // fusing head-mean (x0.25), node-mean (x1/16) and bias -> grs directly.
#pragma unroll
    for (int i = 0; i < 16; ++i) {
      acc[i] += __shfl_xor(acc[i], 1);
      acc[i] += __shfl_xor(acc[i], 2);
      acc[i] += __shfl_xor(acc[i], 4);
      acc[i] += __shfl_xor(acc[i], 8);
    }
    if (l31 < 4) {
      float4 ov;
      if (l31 == 0)      { ov.x = acc[0];  ov.y = acc[1];  ov.z = acc[2];  ov.w = acc[3];  }
      else if (l31 == 1) { ov.x = acc[4];  ov.y = acc[5];  ov.z = acc[6];  ov.w = acc[7];  }
      else if (l31 == 2) { ov.x = acc[8];  ov.y = acc[9];  ov.z = acc[10]; ov.w = acc[11]; }
      else               { ov.x = acc[12]; ov.y = acc[13]; ov.z = acc[14]; ov.w = acc[15]; }
      const int c0 = mt*32 + l31*8 + hi*4;
      const float4 bv = *(const float4*)(bias + c0);
      ov.x = fmaf(1.f/64.f, ov.x, bv.x);
      ov.y = fmaf(1.f/64.f, ov.y, bv.y);
      ov.z = fmaf(1.f/64.f, ov.z, bv.z);
      ov.w = fmaf(1.f/64.f, ov.w, bv.w);
      *(float4*)&sm.u.mlp.grs[g][c0] = ov;     // grs overlays dead asd region; ptb untouched
    }
  }
}

extern "C" __global__ void __launch_bounds__(512, 4)
gat_main(const float* __restrict__ xg, const float* __restrict__ b_in,
         const float* __restrict__ bias0, const float* __restrict__ bias1,
         const float* __restrict__ bias2,
         const uint4* __restrict__ wq0, const uint4* __restrict__ wq1,
         const uint4* __restrict__ wq2, const uint4* __restrict__ winq,
         const float* __restrict__ mw1, const float* __restrict__ mb1,
         const float* __restrict__ g1, const float* __restrict__ be1,
         const u32* __restrict__ mwb2, const float* __restrict__ mb2,
         const float* __restrict__ g2, const float* __restrict__ be2,
         float* __restrict__ out, int Btot)
{
  __shared__ SMem sm;
  const int t = threadIdx.x;
  const int b0 = blockIdx.x * GPB;
  if (b0 >= Btot) return;
  const int lane = t & 63, w = t >> 6;
  const int l31 = lane & 31, hi = lane >> 5;

  // ---- in-proj via MFMA: x loaded straight to B-fragments (waves 0-3) ----
  if (w < 4) {
    const int mtC = w & 1, ntN = w >> 1;
    const int gg = ntN*2 + (l31 >> 4), node = l31 & 15;
    float xv[8];
#pragma unroll
    for (int j = 0; j < 8; ++j)
      xv[j] = xg[(size_t)(b0 + gg)*256 + (hi*8 + j)*16 + node];
    union { u32 uu[4]; bf16x8 v; } bcv;
#pragma unroll
    for (int j = 0; j < 4; ++j) bcv.uu[j] = pk2(xv[2*j], xv[2*j+1]);
    const uint4 aw4 = winq[mtC*64 + lane];
    f32x16 acc = ZERO16;
    acc = MFMA32(*(const bf16x8*)&aw4, bcv.v, acc, 0, 0, 0);
    const int row = ntN*32 + l31;
#pragma unroll
    for (int grp = 0; grp < 4; ++grp) {
      const int cb = mtC*32 + grp*8 + hi*4;
      const float4 bv = *(const float4*)(b_in + cb);
      uint2 o;
      o.x = pk2(fmaxf(acc[grp*4+0] + bv.x, 0.f), fmaxf(acc[grp*4+1] + bv.y, 0.f));
      o.y = pk2(fmaxf(acc[grp*4+2] + bv.z, 0.f), fmaxf(acc[grp*4+3] + bv.w, 0.f));
      *(uint2*)(sm.hA + swz(row, 2*cb)) = o;
    }
  }
  __syncthreads();

  // ---- GAT layers ----
  gemm32<4>(sm, wq0, t);   __syncthreads();
  agg32<0>(sm, bias0, t);  __syncthreads();

  gemm32<16>(sm, wq1, t);  __syncthreads();
  agg32<0>(sm, bias1, t);  __syncthreads();

  gemm32<16>(sm, wq2, t);  __syncthreads();
  agg32<1>(sm, bias2, t);  __syncthreads();   // grs ready (pool fused into agg)

  // ---- MLP1 [64]->[128] ----
  const int mg = t >> 7, o = t & 127;
  float a1v = mb1[o];
#pragma unroll 8
  for (int k = 0; k < 64; ++k) a1v = fmaf(sm.u.mlp.grs[mg][k], mw1[k*128 + o], a1v);
  {
    float su = a1v, sq = a1v*a1v;
#pragma unroll
    for (int off = 32; off >= 1; off >>= 1) { su += __shfl_xor(su, off); sq += __shfl_xor(sq, off); }
    if (lane == 0) { sm.u.mlp.red[0][w][0] = su; sm.u.mlp.red[0][w][1] = sq; }
  }
  __syncthreads();
  {
    const float mu = (sm.u.mlp.red[0][2*mg][0] + sm.u.mlp.red[0][2*mg+1][0]) * (1.f/128.f);
    const float mq = (sm.u.mlp.red[0][2*mg][1] + sm.u.mlp.red[0][2*mg+1][1]) * (1.f/128.f);
    const float rstd = rsqrtf(mq - mu*mu + 1e-5f);
    sm.u.mlp.z1[mg][o] = fmaxf((a1v - mu)*rstd*g1[o] + be1[o], 0.f);
  }
  __syncthreads();

  // ---- MLP2 [128]->[256], LN, relu, store ----
  {
    const float2 bb2 = *(const float2*)(mb2 + 2*o);
    float c0 = bb2.x, c1 = bb2.y;
#pragma unroll 8
    for (int k = 0; k < 128; ++k) {
      const float zk = sm.u.mlp.z1[mg][k];
      const u32 uw = mwb2[k*128 + o];
      c0 = fmaf(zk, __uint_as_float(uw << 16), c0);
      c1 = fmaf(zk, __uint_as_float(uw & 0xffff0000u), c1);
    }
    float su = c0 + c1, sq = c0*c0 + c1*c1;
#pragma unroll
    for (int off = 32; off >= 1; off >>= 1) { su += __shfl_xor(su, off); sq += __shfl_xor(sq, off); }
    if (lane == 0) { sm.u.mlp.red[1][w][0] = su; sm.u.mlp.red[1][w][1] = sq; }
    __syncthreads();
    const float mu = (sm.u.mlp.red[1][2*mg][0] + sm.u.mlp.red[1][2*mg+1][0]) * (1.f/256.f);
    const float mq = (sm.u.mlp.red[1][2*mg][1] + sm.u.mlp.red[1][2*mg+1][1]) * (1.f/256.f);
    const float rstd = rsqrtf(mq - mu*mu + 1e-5f);
    const float2 gg2  = *(const float2*)(g2  + 2*o);
    const float2 bbe2 = *(const float2*)(be2 + 2*o);
    float2 ov;
    ov.x = fmaxf((c0 - mu)*rstd*gg2.x + bbe2.x, 0.f);
    ov.y = fmaxf((c1 - mu)*rstd*gg2.y + bbe2.y, 0.f);
    *(float2*)(out + (size_t)(b0 + mg)*256 + 2*o) = ov;
  }
}

// ---- prepass: 32x32x16 B-fragments (9 n-tiles: 8 cols + fused att) + Win A-frags + mw2 bf16 ----
// u16 layout: wf0 @0 (4*9*512=18432); wf1 @18432 (16*9*512=73728); wf2 @92160 (73728);
//             win @165888 (2*512=1024); mw2 @166912 (32768). total 199680.
__global__ void __launch_bounds__(256)
prep_w(const float* __restrict__ w0, const float* __restrict__ as0, const float* __restrict__ ad0,
       const float* __restrict__ w1, const float* __restrict__ as1, const float* __restrict__ ad1,
       const float* __restrict__ w2, const float* __restrict__ as2, const float* __restrict__ ad2,
       const float* __restrict__ w_in, const float* __restrict__ mw2, u16* __restrict__ wf) {
  const int f = blockIdx.x*256 + threadIdx.x;
  if (f >= 199680) return;
  if (f >= 166912) { wf[f] = (u16)f2bf1(mw2[f - 166912]); return; }
  if (f >= 165888) {
    const int local = f - 165888;
    const int nt = local >> 9, lane = (local >> 3) & 63, j = local & 7;
    wf[f] = (u16)f2bf1(w_in[((lane >> 5)*8 + j)*64 + nt*32 + (lane & 31)]);
    return;
  }
  const float *W, *as_, *ad_; int local;
  if (f < 18432)      { W = w0; as_ = as0; ad_ = ad0; local = f; }
  else if (f < 92160) { W = w1; as_ = as1; ad_ = ad1; local = f - 18432; }
  else                { W = w2; as_ = as2; ad_ = ad2; local = f - 92160; }
  const int ks = local / 4608;
  const int r  = local - ks*4608;
  const int nt = r >> 9;
  const int lane = (r >> 3) & 63;
  const int j = r & 7;
  const int k = ks*16 + (lane >> 5)*8 + j;
  const int col = lane & 31;
  float val;
  if (nt < 8) {
    val = W[k*256 + nt*32 + col];
  } else if (col < 8) {
    const int h = col & 3;
    const float* av = (col < 4) ? as_ : ad_;
    float s = 0.f;
    for (int c = 0; c < 64; ++c) s = fmaf(W[k*256 + h*64 + c], av[h*64 + c], s);
    val = s;
  } else {
    val = 0.f;
  }
  wf[f] = (u16)f2bf1(val);
}

extern "C" void kernel_launch(void* const* d_in, const int* in_sizes, int n_in,
                              void* d_out, int out_size, void* d_ws, size_t ws_size,
                              hipStream_t stream) {
  (void)n_in; (void)out_size; (void)ws_size;
  const float* xg   = (const float*)d_in[0];
  const float* w_in = (const float*)d_in[1];
  const float* b_in = (const float*)d_in[2];
  const float* w0   = (const float*)d_in[3];
  const float* as0  = (const float*)d_in[4];
  const float* ad0  = (const float*)d_in[5];
  const float* bi0  = (const float*)d_in[6];
  const float* w1   = (const float*)d_in[7];
  const float* as1  = (const float*)d_in[8];
  const float* ad1  = (const float*)d_in[9];
  const float* bi1  = (const float*)d_in[10];
  const float* w2   = (const float*)d_in[11];
  const float* as2  = (const float*)d_in[12];
  const float* ad2  = (const float*)d_in[13];
  const float* bi2  = (const float*)d_in[14];
  const float* mw1  = (const float*)d_in[15];
  const float* mb1  = (const float*)d_in[16];
  const float* g1   = (const float*)d_in[17];
  const float* be1  = (const float*)d_in[18];
  const float* mw2  = (const float*)d_in[19];
  const float* mb2  = (const float*)d_in[20];
  const float* g2   = (const float*)d_in[21];
  const float* be2  = (const float*)d_in[22];
  float* out = (float*)d_out;

  const int Btot = in_sizes[0] / 256;               // 8192
  u16* wf = (u16*)d_ws;                             // 199680 u16 = 390 KB
  const uint4* wq0  = (const uint4*)wf;
  const uint4* wq1  = (const uint4*)(wf + 18432);
  const uint4* wq2  = (const uint4*)(wf + 92160);
  const uint4* winq = (const uint4*)(wf + 165888);
  const u32*   mwb2 = (const u32*)(wf + 166912);

  hipLaunchKernelGGL(prep_w, dim3(780), dim3(256), 0, stream,
                     w0, as0, ad0, w1, as1, ad1, w2, as2, ad2, w_in, mw2, wf);

  const int nblocks = (Btot + GPB - 1) / GPB;       // 2048
  hipLaunchKernelGGL(gat_main, dim3(nblocks), dim3(512), 0, stream,
                     xg, b_in, bi0, bi1, bi2, wq0, wq1, wq2, winq,
                     mw1, mb1, g1, be1, mwb2, mb2, g2, be2, out, Btot);
}

// Round 11
// 152.855 us; speedup vs baseline: 1.1528x; 1.1528x over previous
//
#include <hip/hip_runtime.h>
#include <hip/hip_bf16.h>

typedef unsigned short u16;
typedef unsigned int   u32;
typedef __attribute__((ext_vector_type(8)))  short bf16x8;
typedef __attribute__((ext_vector_type(16))) float f32x16;

#define GPB 4
#define ZERO16 (f32x16){0.f,0.f,0.f,0.f,0.f,0.f,0.f,0.f,0.f,0.f,0.f,0.f,0.f,0.f,0.f,0.f}
#define MFMA32 __builtin_amdgcn_mfma_f32_32x32x16_bf16

__constant__ int ADJ_DEG[16] = {3,4,4,3, 4,5,5,4, 4,5,5,4, 3,4,4,3};
__constant__ int ADJ_SRC[16][5] = {
  {0,1,4,0,0},   {1,0,2,5,0},   {2,1,3,6,0},   {3,2,7,0,0},
  {4,5,0,8,0},   {5,4,6,1,9},   {6,5,7,2,10},  {7,6,3,11,0},
  {8,9,4,12,0},  {9,8,10,5,13}, {10,9,11,6,14},{11,10,7,15,0},
  {12,13,8,0,0}, {13,12,14,9,0},{14,13,15,10,0},{15,14,11,0,0}
};

struct SMem {
  char hA[64*512];      // bf16 [64 rows][256 cols] row-major, XOR-swizzled
  char hBT[4*256*32];   // bf16 X^T [g][c][node 0..15], 32B rows, XOR swizzled
  union {
    struct { float asd[64][8]; char ptb[16*16*32]; } post;              // 2KB + 8KB (per g,h,d)
    struct { float grs[4][64]; float z1[4][128]; float red[2][8][2]; } mlp;
  } u;
};  // ~74 KB -> 2 blocks/CU

__device__ __forceinline__ int swz(int row, int b) {
  return (row << 9) + (b ^ ((row & 7) << 4) ^ (((row >> 3) & 1) << 5));
}
__device__ __forceinline__ int xswz(int g, int c, int b) {
  return (g << 13) + (c << 5) + (b ^ (((c >> 2) & 1) << 4) ^ (((c >> 3) & 1) << 3));
}
__device__ __forceinline__ int ptbx(int g, int h, int d, int b) {   // b in {0,16}
  return (((g*4 + h)*16 + d) << 5) + (b ^ (((h ^ (d >> 2)) & 1) << 4));
}
__device__ __forceinline__ u32 f2bf1(float x) {
  u32 u = __float_as_uint(x);
  return (u + 0x7fffu + ((u >> 16) & 1u)) >> 16;
}
__device__ __forceinline__ u32 pk2(float a, float b) {
  __hip_bfloat162 h2 = __float22bfloat162_rn(make_float2(a, b));
  union { __hip_bfloat162 h; u32 u; } cv; cv.h = h2; return cv.u;
}
__device__ __forceinline__ bf16x8 hbt_read(const SMem& sm, int g, int c, int hi) {
  union { uint2 u2[2]; bf16x8 v; } cv;
  cv.u2[0] = *(const uint2*)(sm.hBT + xswz(g, c, hi*16));
  cv.u2[1] = *(const uint2*)(sm.hBT + xswz(g, c, hi*16 + 8));
  return cv.v;
}

// ---- GEMM x = h @ W via 32x32x16; wave w owns n-tile w (32 cols), both m-halves.
// Waves 0-1 also compute fused att tile (nt=8) for m-half w, then wave-local softmax -> ptb.
template<int KS>
__device__ __forceinline__ void gemm32(SMem& sm, const uint4* __restrict__ wsrc, int t) {
  const int lane = t & 63, w = t >> 6;
  const int l31 = lane & 31, hi = lane >> 5;
  const bool hasAtt = (w < 2);

  f32x16 acc0 = ZERO16, acc1 = ZERO16, accA = ZERO16;

#pragma unroll 4
  for (int ks = 0; ks < KS; ++ks) {
    const uint4 bw = wsrc[(ks*9 + w)*64 + lane];
    uint4 ba;
    if (hasAtt) ba = wsrc[(ks*9 + 8)*64 + lane];
    const bf16x8 a0 = *(const bf16x8*)(sm.hA + swz(l31,      ks*32 + hi*16));
    const bf16x8 a1 = *(const bf16x8*)(sm.hA + swz(32 + l31, ks*32 + hi*16));
    acc0 = MFMA32(a0, *(const bf16x8*)&bw, acc0, 0, 0, 0);
    acc1 = MFMA32(a1, *(const bf16x8*)&bw, acc1, 0, 0, 0);
    if (hasAtt) accA = MFMA32((w == 0) ? a0 : a1, *(const bf16x8*)&ba, accA, 0, 0, 0);
  }

  // X^T epilogue: lane = col c, rows r = (reg&3)+8*(reg>>2)+4*hi
  const int c = w*32 + l31;
#pragma unroll
  for (int mh = 0; mh < 2; ++mh) {
    const f32x16 A = mh ? acc1 : acc0;
#pragma unroll
    for (int grp = 0; grp < 4; ++grp) {
      const int g  = mh*2 + (grp >> 1);
      const int n0 = (grp & 1)*8 + hi*4;
      uint2 o;
      o.x = pk2(A[grp*4+0], A[grp*4+1]);
      o.y = pk2(A[grp*4+2], A[grp*4+3]);
      *(uint2*)(sm.hBT + xswz(g, c, n0*2)) = o;
    }
  }

  if (hasAtt) {
    if (l31 < 8) {
#pragma unroll
      for (int grp = 0; grp < 4; ++grp) {
        const int g  = w*2 + (grp >> 1);
        const int n0 = (grp & 1)*8 + hi*4;
#pragma unroll
        for (int i = 0; i < 4; ++i)
          sm.u.post.asd[g*16 + n0 + i][l31] = accA[grp*4+i];
      }
    }
    // wave-local softmax (same-wave LDS ops are in-order; no block barrier needed)
    const int g = w*2 + hi;
    const int h = lane & 3;
#pragma unroll
    for (int dd = 0; dd < 2; ++dd) {
      const int d = ((lane >> 2) & 7) + dd*8;
      const int deg = ADJ_DEG[d];
      const float advl = sm.u.post.asd[g*16 + d][4 + h];
      float al[5]; int srcs[5];
      float m = -1e30f;
#pragma unroll
      for (int k = 0; k < 5; ++k) {
        srcs[k] = (k < deg) ? ADJ_SRC[d][k] : 99;
        float v = 0.f;
        if (k < deg) {
          v = sm.u.post.asd[g*16 + srcs[k]][h] + advl;
          v = (v > 0.f) ? v : 0.2f * v;          // leaky_relu 0.2
          m = fmaxf(m, v);
        }
        al[k] = v;
      }
      float ssum = 0.f;
#pragma unroll
      for (int k = 0; k < 5; ++k)
        if (k < deg) { const float e = __expf(al[k] - m); al[k] = e; ssum += e; }
      const float inv = 1.f / ssum;
      float p[16];
#pragma unroll
      for (int s = 0; s < 16; ++s) {
        float v = 0.f;
#pragma unroll
        for (int k = 0; k < 5; ++k) v = (srcs[k] == s) ? al[k] * inv : v;
        p[s] = v;
      }
      uint4 lo, hh;
      lo.x = pk2(p[0],p[1]);   lo.y = pk2(p[2],p[3]);   lo.z = pk2(p[4],p[5]);   lo.w = pk2(p[6],p[7]);
      hh.x = pk2(p[8],p[9]);   hh.y = pk2(p[10],p[11]); hh.z = pk2(p[12],p[13]); hh.w = pk2(p[14],p[15]);
      *(uint4*)(sm.u.post.ptb + ptbx(g, h, d, 0))  = lo;   // logical s 0-7
      *(uint4*)(sm.u.post.ptb + ptbx(g, h, d, 16)) = hh;   // logical s 8-15
    }
  }
}

// ---- aggregation: D = X^T @ P_h^T via 32x32x16 ----
template<int MODE>   // 0: concat+bias+relu -> hA; 1: mean heads+nodes + bias -> grs directly
__device__ __forceinline__ void agg32(SMem& sm, const float* __restrict__ bias, int t) {
  const int lane = t & 63, w = t >> 6;
  const int l31 = lane & 31, hi = lane >> 5;
  const int g = w >> 1;
  const bf16x8 zero8 = {0,0,0,0,0,0,0,0};

  if (MODE == 0) {
#pragma unroll
    for (int i = 0; i < 4; ++i) {
      const int mt = (w & 1)*4 + i;
      const int h = mt >> 1;                      // head owning this 32-col feature tile
      bf16x8 pb = zero8;
      if (l31 < 16)
        pb = *(const bf16x8*)(sm.u.post.ptb + ptbx(g, h, l31, hi*16));
      const bf16x8 a = hbt_read(sm, g, mt*32 + l31, hi);
      f32x16 acc = ZERO16;
      acc = MFMA32(a, pb, acc, 0, 0, 0);
      if (l31 < 16) {
        const int row = g*16 + l31;
#pragma unroll
        for (int grp = 0; grp < 4; ++grp) {
          const int cb = mt*32 + grp*8 + hi*4;
          const float4 bv = *(const float4*)(bias + cb);
          uint2 o;
          o.x = pk2(fmaxf(acc[grp*4+0] + bv.x, 0.f), fmaxf(acc[grp*4+1] + bv.y, 0.f));
          o.y = pk2(fmaxf(acc[grp*4+2] + bv.z, 0.f), fmaxf(acc[grp*4+3] + bv.w, 0.f));
          *(uint2*)(sm.hA + swz(row, 2*cb)) = o;
        }
      }
    }
  } else {
    const int mt = w & 1;
    f32x16 acc = ZERO16;
#pragma unroll
    for (int h = 0; h < 4; ++h) {                 // chain heads with per-head P
      bf16x8 pb = zero8;
      if (l31 < 16)
        pb = *(const bf16x8*)(sm.u.post.ptb + ptbx(g, h, l31, hi*16));
      const bf16x8 a = hbt_read(sm, g, h*64 + mt*32 + l31, hi);
      acc = MFMA32(a, pb, acc, 0, 0, 0);
    }
    // sum over dst nodes (cols = lanes l31 0..15; 16..31 hold zeros) via shuffles,
    // fusing head-mean (x0.25), node-mean (x1/16) and bias -> grs directly.
#pragma unroll
    for (int i = 0; i < 16; ++i) {
      acc[i] += __shfl_xor(acc[i], 1);
      acc[i] += __shfl_xor(acc[i], 2);
      acc[i] += __shfl_xor(acc[i], 4);
      acc[i] += __shfl_xor(acc[i], 8);
    }
    if (l31 < 4) {
      float4 ov;
      if (l31 == 0)      { ov.x = acc[0];  ov.y = acc[1];  ov.z = acc[2];  ov.w = acc[3];  }
      else if (l31 == 1) { ov.x = acc[4];  ov.y = acc[5];  ov.z = acc[6];  ov.w = acc[7];  }
      else if (l31 == 2) { ov.x = acc[8];  ov.y = acc[9];  ov.z = acc[10]; ov.w = acc[11]; }
      else               { ov.x = acc[12]; ov.y = acc[13]; ov.z = acc[14]; ov.w = acc[15]; }
      const int c0 = mt*32 + l31*8 + hi*4;
      const float4 bv = *(const float4*)(bias + c0);
      ov.x = fmaf(1.f/64.f, ov.x, bv.x);
      ov.y = fmaf(1.f/64.f, ov.y, bv.y);
      ov.z = fmaf(1.f/64.f, ov.z, bv.z);
      ov.w = fmaf(1.f/64.f, ov.w, bv.w);
      *(float4*)&sm.u.mlp.grs[g][c0] = ov;     // grs overlays dead asd region; ptb untouched
    }
  }
}

extern "C" __global__ void __launch_bounds__(512, 4)
gat_main(const float* __restrict__ xg, const float* __restrict__ b_in,
         const float* __restrict__ bias0, const float* __restrict__ bias1,
         const float* __restrict__ bias2,
         const uint4* __restrict__ wq0, const uint4* __restrict__ wq1,
         const uint4* __restrict__ wq2, const uint4* __restrict__ winq,
         const float* __restrict__ mw1, const float* __restrict__ mb1,
         const float* __restrict__ g1, const float* __restrict__ be1,
         const u32* __restrict__ mwb2, const float* __restrict__ mb2,
         const float* __restrict__ g2, const float* __restrict__ be2,
         float* __restrict__ out, int Btot)
{
  __shared__ SMem sm;
  const int t = threadIdx.x;
  const int b0 = blockIdx.x * GPB;
  if (b0 >= Btot) return;
  const int lane = t & 63, w = t >> 6;
  const int l31 = lane & 31, hi = lane >> 5;

  // ---- in-proj via MFMA: x loaded straight to B-fragments (waves 0-3) ----
  if (w < 4) {
    const int mtC = w & 1, ntN = w >> 1;
    const int gg = ntN*2 + (l31 >> 4), node = l31 & 15;
    float xv[8];
#pragma unroll
    for (int j = 0; j < 8; ++j)
      xv[j] = xg[(size_t)(b0 + gg)*256 + (hi*8 + j)*16 + node];
    union { u32 uu[4]; bf16x8 v; } bcv;
#pragma unroll
    for (int j = 0; j < 4; ++j) bcv.uu[j] = pk2(xv[2*j], xv[2*j+1]);
    const uint4 aw4 = winq[mtC*64 + lane];
    f32x16 acc = ZERO16;
    acc = MFMA32(*(const bf16x8*)&aw4, bcv.v, acc, 0, 0, 0);
    const int row = ntN*32 + l31;
#pragma unroll
    for (int grp = 0; grp < 4; ++grp) {
      const int cb = mtC*32 + grp*8 + hi*4;
      const float4 bv = *(const float4*)(b_in + cb);
      uint2 o;
      o.x = pk2(fmaxf(acc[grp*4+0] + bv.x, 0.f), fmaxf(acc[grp*4+1] + bv.y, 0.f));
      o.y = pk2(fmaxf(acc[grp*4+2] + bv.z, 0.f), fmaxf(acc[grp*4+3] + bv.w, 0.f));
      *(uint2*)(sm.hA + swz(row, 2*cb)) = o;
    }
  }
  __syncthreads();

  // ---- GAT layers ----
  gemm32<4>(sm, wq0, t);   __syncthreads();
  agg32<0>(sm, bias0, t);  __syncthreads();

  gemm32<16>(sm, wq1, t);  __syncthreads();
  agg32<0>(sm, bias1, t);  __syncthreads();

  gemm32<16>(sm, wq2, t);  __syncthreads();
  agg32<1>(sm, bias2, t);  __syncthreads();   // grs ready (pool fused into agg)

  // ---- MLP1 [64]->[128] ----
  const int mg = t >> 7, o = t & 127;
  float a1v = mb1[o];
#pragma unroll 8
  for (int k = 0; k < 64; ++k) a1v = fmaf(sm.u.mlp.grs[mg][k], mw1[k*128 + o], a1v);
  {
    float su = a1v, sq = a1v*a1v;
#pragma unroll
    for (int off = 32; off >= 1; off >>= 1) { su += __shfl_xor(su, off); sq += __shfl_xor(sq, off); }
    if (lane == 0) { sm.u.mlp.red[0][w][0] = su; sm.u.mlp.red[0][w][1] = sq; }
  }
  __syncthreads();
  {
    const float mu = (sm.u.mlp.red[0][2*mg][0] + sm.u.mlp.red[0][2*mg+1][0]) * (1.f/128.f);
    const float mq = (sm.u.mlp.red[0][2*mg][1] + sm.u.mlp.red[0][2*mg+1][1]) * (1.f/128.f);
    const float rstd = rsqrtf(mq - mu*mu + 1e-5f);
    sm.u.mlp.z1[mg][o] = fmaxf((a1v - mu)*rstd*g1[o] + be1[o], 0.f);
  }
  __syncthreads();

  // ---- MLP2 [128]->[256], LN, relu, store ----
  {
    const float2 bb2 = *(const float2*)(mb2 + 2*o);
    float c0 = bb2.x, c1 = bb2.y;
#pragma unroll 8
    for (int k = 0; k < 128; ++k) {
      const float zk = sm.u.mlp.z1[mg][k];
      const u32 uw = mwb2[k*128 + o];
      c0 = fmaf(zk, __uint_as_float(uw << 16), c0);
      c1 = fmaf(zk, __uint_as_float(uw & 0xffff0000u), c1);
    }
    float su = c0 + c1, sq = c0*c0 + c1*c1;
#pragma unroll
    for (int off = 32; off >= 1; off >>= 1) { su += __shfl_xor(su, off); sq += __shfl_xor(sq, off); }
    if (lane == 0) { sm.u.mlp.red[1][w][0] = su; sm.u.mlp.red[1][w][1] = sq; }
    __syncthreads();
    const float mu = (sm.u.mlp.red[1][2*mg][0] + sm.u.mlp.red[1][2*mg+1][0]) * (1.f/256.f);
    const float mq = (sm.u.mlp.red[1][2*mg][1] + sm.u.mlp.red[1][2*mg+1][1]) * (1.f/256.f);
    const float rstd = rsqrtf(mq - mu*mu + 1e-5f);
    const float2 gg2  = *(const float2*)(g2  + 2*o);
    const float2 bbe2 = *(const float2*)(be2 + 2*o);
    float2 ov;
    ov.x = fmaxf((c0 - mu)*rstd*gg2.x + bbe2.x, 0.f);
    ov.y = fmaxf((c1 - mu)*rstd*gg2.y + bbe2.y, 0.f);
    *(float2*)(out + (size_t)(b0 + mg)*256 + 2*o) = ov;
  }
}

// ---- prepass: 32x32x16 B-fragments (9 n-tiles: 8 cols + fused att) + Win A-frags + mw2 bf16 ----
// u16 layout: wf0 @0 (4*9*512=18432); wf1 @18432 (16*9*512=73728); wf2 @92160 (73728);
//             win @165888 (2*512=1024); mw2 @166912 (32768). total 199680.
__global__ void __launch_bounds__(256)
prep_w(const float* __restrict__ w0, const float* __restrict__ as0, const float* __restrict__ ad0,
       const float* __restrict__ w1, const float* __restrict__ as1, const float* __restrict__ ad1,
       const float* __restrict__ w2, const float* __restrict__ as2, const float* __restrict__ ad2,
       const float* __restrict__ w_in, const float* __restrict__ mw2, u16* __restrict__ wf) {
  const int f = blockIdx.x*256 + threadIdx.x;
  if (f >= 199680) return;
  if (f >= 166912) { wf[f] = (u16)f2bf1(mw2[f - 166912]); return; }
  if (f >= 165888) {
    const int local = f - 165888;
    const int nt = local >> 9, lane = (local >> 3) & 63, j = local & 7;
    wf[f] = (u16)f2bf1(w_in[((lane >> 5)*8 + j)*64 + nt*32 + (lane & 31)]);
    return;
  }
  const float *W, *as_, *ad_; int local;
  if (f < 18432)      { W = w0; as_ = as0; ad_ = ad0; local = f; }
  else if (f < 92160) { W = w1; as_ = as1; ad_ = ad1; local = f - 18432; }
  else                { W = w2; as_ = as2; ad_ = ad2; local = f - 92160; }
  const int ks = local / 4608;
  const int r  = local - ks*4608;
  const int nt = r >> 9;
  const int lane = (r >> 3) & 63;
  const int j = r & 7;
  const int k = ks*16 + (lane >> 5)*8 + j;
  const int col = lane & 31;
  float val;
  if (nt < 8) {
    val = W[k*256 + nt*32 + col];
  } else if (col < 8) {
    const int h = col & 3;
    const float* av = (col < 4) ? as_ : ad_;
    float s = 0.f;
    for (int c = 0; c < 64; ++c) s = fmaf(W[k*256 + h*64 + c], av[h*64 + c], s);
    val = s;
  } else {
    val = 0.f;
  }
  wf[f] = (u16)f2bf1(val);
}

extern "C" void kernel_launch(void* const* d_in, const int* in_sizes, int n_in,
                              void* d_out, int out_size, void* d_ws, size_t ws_size,
                              hipStream_t stream) {
  (void)n_in; (void)out_size; (void)ws_size;
  const float* xg   = (const float*)d_in[0];
  const float* w_in = (const float*)d_in[1];
  const float* b_in = (const float*)d_in[2];
  const float* w0   = (const float*)d_in[3];
  const float* as0  = (const float*)d_in[4];
  const float* ad0  = (const float*)d_in[5];
  const float* bi0  = (const float*)d_in[6];
  const float* w1   = (const float*)d_in[7];
  const float* as1  = (const float*)d_in[8];
  const float* ad1  = (const float*)d_in[9];
  const float* bi1  = (const float*)d_in[10];
  const float* w2   = (const float*)d_in[11];
  const float* as2  = (const float*)d_in[12];
  const float* ad2  = (const float*)d_in[13];
  const float* bi2  = (const float*)d_in[14];
  const float* mw1  = (const float*)d_in[15];
  const float* mb1  = (const float*)d_in[16];
  const float* g1   = (const float*)d_in[17];
  const float* be1  = (const float*)d_in[18];
  const float* mw2  = (const float*)d_in[19];
  const float* mb2  = (const float*)d_in[20];
  const float* g2   = (const float*)d_in[21];
  const float* be2  = (const float*)d_in[22];
  float* out = (float*)d_out;

  const int Btot = in_sizes[0] / 256;               // 8192
  u16* wf = (u16*)d_ws;                             // 199680 u16 = 390 KB
  const uint4* wq0  = (const uint4*)wf;
  const uint4* wq1  = (const uint4*)(wf + 18432);
  const uint4* wq2  = (const uint4*)(wf + 92160);
  const uint4* winq = (const uint4*)(wf + 165888);
  const u32*   mwb2 = (const u32*)(wf + 166912);

  hipLaunchKernelGGL(prep_w, dim3(780), dim3(256), 0, stream,
                     w0, as0, ad0, w1, as1, ad1, w2, as2, ad2, w_in, mw2, wf);

  const int nblocks = (Btot + GPB - 1) / GPB;       // 2048
  hipLaunchKernelGGL(gat_main, dim3(nblocks), dim3(512), 0, stream,
                     xg, b_in, bi0, bi1, bi2, wq0, wq1, wq2, winq,
                     mw1, mb1, g1, be1, mwb2, mb2, g2, be2, out, Btot);
}

// Round 12
// 151.463 us; speedup vs baseline: 1.1634x; 1.0092x over previous
//
#include <hip/hip_runtime.h>
#include <hip/hip_bf16.h>

typedef unsigned short u16;
typedef unsigned int   u32;
typedef __attribute__((ext_vector_type(8)))  short bf16x8;
typedef __attribute__((ext_vector_type(16))) float f32x16;

#define GPB 4
#define ZERO16 (f32x16){0.f,0.f,0.f,0.f,0.f,0.f,0.f,0.f,0.f,0.f,0.f,0.f,0.f,0.f,0.f,0.f}
#define MFMA32 __builtin_amdgcn_mfma_f32_32x32x16_bf16

__constant__ int ADJ_DEG[16] = {3,4,4,3, 4,5,5,4, 4,5,5,4, 3,4,4,3};
__constant__ int ADJ_SRC[16][5] = {
  {0,1,4,0,0},   {1,0,2,5,0},   {2,1,3,6,0},   {3,2,7,0,0},
  {4,5,0,8,0},   {5,4,6,1,9},   {6,5,7,2,10},  {7,6,3,11,0},
  {8,9,4,12,0},  {9,8,10,5,13}, {10,9,11,6,14},{11,10,7,15,0},
  {12,13,8,0,0}, {13,12,14,9,0},{14,13,15,10,0},{15,14,11,0,0}
};

struct SMem {
  char hA[64*512];      // bf16 [64 rows][256 cols] row-major, XOR-swizzled
  char hBT[4*256*32];   // bf16 X^T [g][c][node 0..15], 32B rows, XOR swizzled
  struct { float asd[64][8]; char ptb[16*16*32]; } post;   // 2KB + 8KB (per g,h,d)
};  // ~74 KB -> 2 blocks/CU

__device__ __forceinline__ int swz(int row, int b) {
  return (row << 9) + (b ^ ((row & 7) << 4) ^ (((row >> 3) & 1) << 5));
}
__device__ __forceinline__ int xswz(int g, int c, int b) {
  return (g << 13) + (c << 5) + (b ^ (((c >> 2) & 1) << 4) ^ (((c >> 3) & 1) << 3));
}
__device__ __forceinline__ int ptbx(int g, int h, int d, int b) {   // b in {0,16}
  return (((g*4 + h)*16 + d) << 5) + (b ^ (((h ^ (d >> 2)) & 1) << 4));
}
__device__ __forceinline__ u32 f2bf1(float x) {
  u32 u = __float_as_uint(x);
  return (u + 0x7fffu + ((u >> 16) & 1u)) >> 16;
}
__device__ __forceinline__ u32 pk2(float a, float b) {
  __hip_bfloat162 h2 = __float22bfloat162_rn(make_float2(a, b));
  union { __hip_bfloat162 h; u32 u; } cv; cv.h = h2; return cv.u;
}
__device__ __forceinline__ bf16x8 hbt_read(const SMem& sm, int g, int c, int hi) {
  union { uint2 u2[2]; bf16x8 v; } cv;
  cv.u2[0] = *(const uint2*)(sm.hBT + xswz(g, c, hi*16));
  cv.u2[1] = *(const uint2*)(sm.hBT + xswz(g, c, hi*16 + 8));
  return cv.v;
}

// ---- GEMM x = h @ W via 32x32x16; wave w owns n-tile w (32 cols), both m-halves.
// Waves 0-1 also compute fused att tile (nt=8) for m-half w, then wave-local softmax -> ptb.
template<int KS>
__device__ __forceinline__ void gemm32(SMem& sm, const uint4* __restrict__ wsrc, int t) {
  const int lane = t & 63, w = t >> 6;
  const int l31 = lane & 31, hi = lane >> 5;
  const bool hasAtt = (w < 2);

  f32x16 acc0 = ZERO16, acc1 = ZERO16, accA = ZERO16;

#pragma unroll 4
  for (int ks = 0; ks < KS; ++ks) {
    const uint4 bw = wsrc[(ks*9 + w)*64 + lane];
    uint4 ba;
    if (hasAtt) ba = wsrc[(ks*9 + 8)*64 + lane];
    const bf16x8 a0 = *(const bf16x8*)(sm.hA + swz(l31,      ks*32 + hi*16));
    const bf16x8 a1 = *(const bf16x8*)(sm.hA + swz(32 + l31, ks*32 + hi*16));
    acc0 = MFMA32(a0, *(const bf16x8*)&bw, acc0, 0, 0, 0);
    acc1 = MFMA32(a1, *(const bf16x8*)&bw, acc1, 0, 0, 0);
    if (hasAtt) accA = MFMA32((w == 0) ? a0 : a1, *(const bf16x8*)&ba, accA, 0, 0, 0);
  }

  // X^T epilogue: lane = col c, rows r = (reg&3)+8*(reg>>2)+4*hi
  const int c = w*32 + l31;
#pragma unroll
  for (int mh = 0; mh < 2; ++mh) {
    const f32x16 A = mh ? acc1 : acc0;
#pragma unroll
    for (int grp = 0; grp < 4; ++grp) {
      const int g  = mh*2 + (grp >> 1);
      const int n0 = (grp & 1)*8 + hi*4;
      uint2 o;
      o.x = pk2(A[grp*4+0], A[grp*4+1]);
      o.y = pk2(A[grp*4+2], A[grp*4+3]);
      *(uint2*)(sm.hBT + xswz(g, c, n0*2)) = o;
    }
  }

  if (hasAtt) {
    if (l31 < 8) {
#pragma unroll
      for (int grp = 0; grp < 4; ++grp) {
        const int g  = w*2 + (grp >> 1);
        const int n0 = (grp & 1)*8 + hi*4;
#pragma unroll
        for (int i = 0; i < 4; ++i)
          sm.post.asd[g*16 + n0 + i][l31] = accA[grp*4+i];
      }
    }
    // wave-local softmax (same-wave LDS ops are in-order; no block barrier needed)
    const int g = w*2 + hi;
    const int h = lane & 3;
#pragma unroll
    for (int dd = 0; dd < 2; ++dd) {
      const int d = ((lane >> 2) & 7) + dd*8;
      const int deg = ADJ_DEG[d];
      const float advl = sm.post.asd[g*16 + d][4 + h];
      float al[5]; int srcs[5];
      float m = -1e30f;
#pragma unroll
      for (int k = 0; k < 5; ++k) {
        srcs[k] = (k < deg) ? ADJ_SRC[d][k] : 99;
        float v = 0.f;
        if (k < deg) {
          v = sm.post.asd[g*16 + srcs[k]][h] + advl;
          v = (v > 0.f) ? v : 0.2f * v;          // leaky_relu 0.2
          m = fmaxf(m, v);
        }
        al[k] = v;
      }
      float ssum = 0.f;
#pragma unroll
      for (int k = 0; k < 5; ++k)
        if (k < deg) { const float e = __expf(al[k] - m); al[k] = e; ssum += e; }
      const float inv = 1.f / ssum;
      float p[16];
#pragma unroll
      for (int s = 0; s < 16; ++s) {
        float v = 0.f;
#pragma unroll
        for (int k = 0; k < 5; ++k) v = (srcs[k] == s) ? al[k] * inv : v;
        p[s] = v;
      }
      uint4 lo, hh;
      lo.x = pk2(p[0],p[1]);   lo.y = pk2(p[2],p[3]);   lo.z = pk2(p[4],p[5]);   lo.w = pk2(p[6],p[7]);
      hh.x = pk2(p[8],p[9]);   hh.y = pk2(p[10],p[11]); hh.z = pk2(p[12],p[13]); hh.w = pk2(p[14],p[15]);
      *(uint4*)(sm.post.ptb + ptbx(g, h, d, 0))  = lo;   // logical s 0-7
      *(uint4*)(sm.post.ptb + ptbx(g, h, d, 16)) = hh;   // logical s 8-15
    }
  }
}

// ---- aggregation: D = X^T @ P_h^T via 32x32x16 ----
template<int MODE>   // 0: concat+bias+relu -> hA; 1: mean heads+nodes + bias -> gr (global)
__device__ __forceinline__ void agg32(SMem& sm, const float* __restrict__ bias, int t,
                                      float* __restrict__ gr, int b0) {
  const int lane = t & 63, w = t >> 6;
  const int l31 = lane & 31, hi = lane >> 5;
  const int g = w >> 1;
  const bf16x8 zero8 = {0,0,0,0,0,0,0,0};

  if (MODE == 0) {
#pragma unroll
    for (int i = 0; i < 4; ++i) {
      const int mt = (w & 1)*4 + i;
      const int h = mt >> 1;                      // head owning this 32-col feature tile
      bf16x8 pb = zero8;
      if (l31 < 16)
        pb = *(const bf16x8*)(sm.post.ptb + ptbx(g, h, l31, hi*16));
      const bf16x8 a = hbt_read(sm, g, mt*32 + l31, hi);
      f32x16 acc = ZERO16;
      acc = MFMA32(a, pb, acc, 0, 0, 0);
      if (l31 < 16) {
        const int row = g*16 + l31;
#pragma unroll
        for (int grp = 0; grp < 4; ++grp) {
          const int cb = mt*32 + grp*8 + hi*4;
          const float4 bv = *(const float4*)(bias + cb);
          uint2 o;
          o.x = pk2(fmaxf(acc[grp*4+0] + bv.x, 0.f), fmaxf(acc[grp*4+1] + bv.y, 0.f));
          o.y = pk2(fmaxf(acc[grp*4+2] + bv.z, 0.f), fmaxf(acc[grp*4+3] + bv.w, 0.f));
          *(uint2*)(sm.hA + swz(row, 2*cb)) = o;
        }
      }
    }
  } else {
    const int mt = w & 1;
    f32x16 acc = ZERO16;
#pragma unroll
    for (int h = 0; h < 4; ++h) {                 // chain heads with per-head P
      bf16x8 pb = zero8;
      if (l31 < 16)
        pb = *(const bf16x8*)(sm.post.ptb + ptbx(g, h, l31, hi*16));
      const bf16x8 a = hbt_read(sm, g, h*64 + mt*32 + l31, hi);
      acc = MFMA32(a, pb, acc, 0, 0, 0);
    }
    // sum over dst nodes (cols = lanes l31 0..15; 16..31 hold zeros) via shuffles,
    // fusing head-mean (x0.25), node-mean (x1/16) and bias -> gr (global) directly.
#pragma unroll
    for (int i = 0; i < 16; ++i) {
      acc[i] += __shfl_xor(acc[i], 1);
      acc[i] += __shfl_xor(acc[i], 2);
      acc[i] += __shfl_xor(acc[i], 4);
      acc[i] += __shfl_xor(acc[i], 8);
    }
    if (l31 < 4) {
      float4 ov;
      if (l31 == 0)      { ov.x = acc[0];  ov.y = acc[1];  ov.z = acc[2];  ov.w = acc[3];  }
      else if (l31 == 1) { ov.x = acc[4];  ov.y = acc[5];  ov.z = acc[6];  ov.w = acc[7];  }
      else if (l31 == 2) { ov.x = acc[8];  ov.y = acc[9];  ov.z = acc[10]; ov.w = acc[11]; }
      else               { ov.x = acc[12]; ov.y = acc[13]; ov.z = acc[14]; ov.w = acc[15]; }
      const int c0 = mt*32 + l31*8 + hi*4;
      const float4 bv = *(const float4*)(bias + c0);
      ov.x = fmaf(1.f/64.f, ov.x, bv.x);
      ov.y = fmaf(1.f/64.f, ov.y, bv.y);
      ov.z = fmaf(1.f/64.f, ov.z, bv.z);
      ov.w = fmaf(1.f/64.f, ov.w, bv.w);
      *(float4*)(gr + (size_t)(b0 + g)*64 + c0) = ov;
    }
  }
}

extern "C" __global__ void __launch_bounds__(512, 4)
gat_main(const float* __restrict__ xg, const float* __restrict__ b_in,
         const float* __restrict__ bias0, const float* __restrict__ bias1,
         const float* __restrict__ bias2,
         const uint4* __restrict__ wq0, const uint4* __restrict__ wq1,
         const uint4* __restrict__ wq2, const uint4* __restrict__ winq,
         float* __restrict__ gr, int Btot)
{
  __shared__ SMem sm;
  const int t = threadIdx.x;
  const int b0 = blockIdx.x * GPB;
  if (b0 >= Btot) return;
  const int lane = t & 63, w = t >> 6;
  const int l31 = lane & 31, hi = lane >> 5;

  // ---- in-proj via MFMA: x loaded straight to B-fragments (waves 0-3) ----
  if (w < 4) {
    const int mtC = w & 1, ntN = w >> 1;
    const int gg = ntN*2 + (l31 >> 4), node = l31 & 15;
    float xv[8];
#pragma unroll
    for (int j = 0; j < 8; ++j)
      xv[j] = xg[(size_t)(b0 + gg)*256 + (hi*8 + j)*16 + node];
    union { u32 uu[4]; bf16x8 v; } bcv;
#pragma unroll
    for (int j = 0; j < 4; ++j) bcv.uu[j] = pk2(xv[2*j], xv[2*j+1]);
    const uint4 aw4 = winq[mtC*64 + lane];
    f32x16 acc = ZERO16;
    acc = MFMA32(*(const bf16x8*)&aw4, bcv.v, acc, 0, 0, 0);
    const int row = ntN*32 + l31;
#pragma unroll
    for (int grp = 0; grp < 4; ++grp) {
      const int cb = mtC*32 + grp*8 + hi*4;
      const float4 bv = *(const float4*)(b_in + cb);
      uint2 o;
      o.x = pk2(fmaxf(acc[grp*4+0] + bv.x, 0.f), fmaxf(acc[grp*4+1] + bv.y, 0.f));
      o.y = pk2(fmaxf(acc[grp*4+2] + bv.z, 0.f), fmaxf(acc[grp*4+3] + bv.w, 0.f));
      *(uint2*)(sm.hA + swz(row, 2*cb)) = o;
    }
  }
  __syncthreads();

  // ---- GAT layers ----
  gemm32<4>(sm, wq0, t);            __syncthreads();
  agg32<0>(sm, bias0, t, gr, b0);   __syncthreads();

  gemm32<16>(sm, wq1, t);           __syncthreads();
  agg32<0>(sm, bias1, t, gr, b0);   __syncthreads();

  gemm32<16>(sm, wq2, t);           __syncthreads();
  agg32<1>(sm, bias2, t, gr, b0);   // writes gr to global; block retires
}

// ---- MLP kernel: 4 graphs/block, weights from L2, ~2.5 KB LDS -> high occupancy ----
extern "C" __global__ void __launch_bounds__(512)
mlp_kernel(const float* __restrict__ mw1, const float* __restrict__ mb1,
           const float* __restrict__ g1, const float* __restrict__ be1,
           const u32* __restrict__ mwb2, const float* __restrict__ mb2,
           const float* __restrict__ g2, const float* __restrict__ be2,
           const float* __restrict__ gr, float* __restrict__ out, int Btot)
{
  __shared__ float grs[4][64];
  __shared__ float z1[4][128];
  __shared__ float red[2][8][2];
  const int t = threadIdx.x;
  const int b0 = blockIdx.x * 4;
  if (b0 >= Btot) return;
  if (t < 256) grs[t >> 6][t & 63] = gr[(size_t)b0*64 + t];
  __syncthreads();

  const int mg = t >> 7, o = t & 127, w = t >> 6, lane = t & 63;

  // MLP1 [64]->[128]
  float a1v = mb1[o];
#pragma unroll 8
  for (int k = 0; k < 64; ++k) a1v = fmaf(grs[mg][k], mw1[k*128 + o], a1v);
  {
    float su = a1v, sq = a1v*a1v;
#pragma unroll
    for (int off = 32; off >= 1; off >>= 1) { su += __shfl_xor(su, off); sq += __shfl_xor(sq, off); }
    if (lane == 0) { red[0][w][0] = su; red[0][w][1] = sq; }
  }
  __syncthreads();
  {
    const float mu = (red[0][2*mg][0] + red[0][2*mg+1][0]) * (1.f/128.f);
    const float mq = (red[0][2*mg][1] + red[0][2*mg+1][1]) * (1.f/128.f);
    const float rstd = rsqrtf(mq - mu*mu + 1e-5f);
    z1[mg][o] = fmaxf((a1v - mu)*rstd*g1[o] + be1[o], 0.f);
  }
  __syncthreads();

  // MLP2 [128]->[256], LN, relu, store
  {
    const float2 bb2 = *(const float2*)(mb2 + 2*o);
    float c0 = bb2.x, c1 = bb2.y;
#pragma unroll 8
    for (int k = 0; k < 128; ++k) {
      const float zk = z1[mg][k];
      const u32 uw = mwb2[k*128 + o];
      c0 = fmaf(zk, __uint_as_float(uw << 16), c0);
      c1 = fmaf(zk, __uint_as_float(uw & 0xffff0000u), c1);
    }
    float su = c0 + c1, sq = c0*c0 + c1*c1;
#pragma unroll
    for (int off = 32; off >= 1; off >>= 1) { su += __shfl_xor(su, off); sq += __shfl_xor(sq, off); }
    if (lane == 0) { red[1][w][0] = su; red[1][w][1] = sq; }
    __syncthreads();
    const float mu = (red[1][2*mg][0] + red[1][2*mg+1][0]) * (1.f/256.f);
    const float mq = (red[1][2*mg][1] + red[1][2*mg+1][1]) * (1.f/256.f);
    const float rstd = rsqrtf(mq - mu*mu + 1e-5f);
    const float2 gg2  = *(const float2*)(g2  + 2*o);
    const float2 bbe2 = *(const float2*)(be2 + 2*o);
    float2 ov;
    ov.x = fmaxf((c0 - mu)*rstd*gg2.x + bbe2.x, 0.f);
    ov.y = fmaxf((c1 - mu)*rstd*gg2.y + bbe2.y, 0.f);
    *(float2*)(out + (size_t)(b0 + mg)*256 + 2*o) = ov;
  }
}

// ---- prepass: 32x32x16 B-fragments (9 n-tiles: 8 cols + fused att) + Win A-frags + mw2 bf16 ----
// u16 layout: wf0 @0 (4*9*512=18432); wf1 @18432 (16*9*512=73728); wf2 @92160 (73728);
//             win @165888 (2*512=1024); mw2 @166912 (32768). total 199680.
__global__ void __launch_bounds__(256)
prep_w(const float* __restrict__ w0, const float* __restrict__ as0, const float* __restrict__ ad0,
       const float* __restrict__ w1, const float* __restrict__ as1, const float* __restrict__ ad1,
       const float* __restrict__ w2, const float* __restrict__ as2, const float* __restrict__ ad2,
       const float* __restrict__ w_in, const float* __restrict__ mw2, u16* __restrict__ wf) {
  const int f = blockIdx.x*256 + threadIdx.x;
  if (f >= 199680) return;
  if (f >= 166912) { wf[f] = (u16)f2bf1(mw2[f - 166912]); return; }
  if (f >= 165888) {
    const int local = f - 165888;
    const int nt = local >> 9, lane = (local >> 3) & 63, j = local & 7;
    wf[f] = (u16)f2bf1(w_in[((lane >> 5)*8 + j)*64 + nt*32 + (lane & 31)]);
    return;
  }
  const float *W, *as_, *ad_; int local;
  if (f < 18432)      { W = w0; as_ = as0; ad_ = ad0; local = f; }
  else if (f < 92160) { W = w1; as_ = as1; ad_ = ad1; local = f - 18432; }
  else                { W = w2; as_ = as2; ad_ = ad2; local = f - 92160; }
  const int ks = local / 4608;
  const int r  = local - ks*4608;
  const int nt = r >> 9;
  const int lane = (r >> 3) & 63;
  const int j = r & 7;
  const int k = ks*16 + (lane >> 5)*8 + j;
  const int col = lane & 31;
  float val;
  if (nt < 8) {
    val = W[k*256 + nt*32 + col];
  } else if (col < 8) {
    const int h = col & 3;
    const float* av = (col < 4) ? as_ : ad_;
    float s = 0.f;
    for (int c = 0; c < 64; ++c) s = fmaf(W[k*256 + h*64 + c], av[h*64 + c], s);
    val = s;
  } else {
    val = 0.f;
  }
  wf[f] = (u16)f2bf1(val);
}

extern "C" void kernel_launch(void* const* d_in, const int* in_sizes, int n_in,
                              void* d_out, int out_size, void* d_ws, size_t ws_size,
                              hipStream_t stream) {
  (void)n_in; (void)out_size; (void)ws_size;
  const float* xg   = (const float*)d_in[0];
  const float* w_in = (const float*)d_in[1];
  const float* b_in = (const float*)d_in[2];
  const float* w0   = (const float*)d_in[3];
  const float* as0  = (const float*)d_in[4];
  const float* ad0  = (const float*)d_in[5];
  const float* bi0  = (const float*)d_in[6];
  const float* w1   = (const float*)d_in[7];
  const float* as1  = (const float*)d_in[8];
  const float* ad1  = (const float*)d_in[9];
  const float* bi1  = (const float*)d_in[10];
  const float* w2   = (const float*)d_in[11];
  const float* as2  = (const float*)d_in[12];
  const float* ad2  = (const float*)d_in[13];
  const float* bi2  = (const float*)d_in[14];
  const float* mw1  = (const float*)d_in[15];
  const float* mb1  = (const float*)d_in[16];
  const float* g1   = (const float*)d_in[17];
  const float* be1  = (const float*)d_in[18];
  const float* mw2  = (const float*)d_in[19];
  const float* mb2  = (const float*)d_in[20];
  const float* g2   = (const float*)d_in[21];
  const float* be2  = (const float*)d_in[22];
  float* out = (float*)d_out;

  const int Btot = in_sizes[0] / 256;               // 8192
  u16* wf = (u16*)d_ws;                             // 199680 u16 = 399360 B
  const uint4* wq0  = (const uint4*)wf;
  const uint4* wq1  = (const uint4*)(wf + 18432);
  const uint4* wq2  = (const uint4*)(wf + 92160);
  const uint4* winq = (const uint4*)(wf + 165888);
  const u32*   mwb2 = (const u32*)(wf + 166912);
  float* gr = (float*)((char*)d_ws + 401408);       // [Btot][64] fp32 = 2 MB

  hipLaunchKernelGGL(prep_w, dim3(780), dim3(256), 0, stream,
                     w0, as0, ad0, w1, as1, ad1, w2, as2, ad2, w_in, mw2, wf);

  const int nblocks = (Btot + GPB - 1) / GPB;       // 2048
  hipLaunchKernelGGL(gat_main, dim3(nblocks), dim3(512), 0, stream,
                     xg, b_in, bi0, bi1, bi2, wq0, wq1, wq2, winq, gr, Btot);

  hipLaunchKernelGGL(mlp_kernel, dim3((Btot + 3) / 4), dim3(512), 0, stream,
                     mw1, mb1, g1, be1, mwb2, mb2, g2, be2, gr, out, Btot);
}

// Round 13
// 141.055 us; speedup vs baseline: 1.2493x; 1.0738x over previous
//
#include <hip/hip_runtime.h>
#include <hip/hip_bf16.h>

typedef unsigned short u16;
typedef unsigned int   u32;
typedef __attribute__((ext_vector_type(8)))  short bf16x8;
typedef __attribute__((ext_vector_type(16))) float f32x16;

#define GPB 4
#define ZERO16 (f32x16){0.f,0.f,0.f,0.f,0.f,0.f,0.f,0.f,0.f,0.f,0.f,0.f,0.f,0.f,0.f,0.f}
#define MFMA32 __builtin_amdgcn_mfma_f32_32x32x16_bf16

__constant__ int ADJ_DEG[16] = {3,4,4,3, 4,5,5,4, 4,5,5,4, 3,4,4,3};
__constant__ int ADJ_SRC[16][5] = {
  {0,1,4,0,0},   {1,0,2,5,0},   {2,1,3,6,0},   {3,2,7,0,0},
  {4,5,0,8,0},   {5,4,6,1,9},   {6,5,7,2,10},  {7,6,3,11,0},
  {8,9,4,12,0},  {9,8,10,5,13}, {10,9,11,6,14},{11,10,7,15,0},
  {12,13,8,0,0}, {13,12,14,9,0},{14,13,15,10,0},{15,14,11,0,0}
};

struct SMem {
  char hA[64*512];      // bf16 [64 rows][256 cols] row-major, XOR-swizzled
  char hBT[4*256*32];   // bf16 X^T [g][c][node 0..15], 32B rows, XOR swizzled
  struct { float asd[64][8]; char ptb[16*16*32]; } post;   // 2KB + 8KB (per g,h,d)
};  // ~74 KB -> 2 blocks/CU

__device__ __forceinline__ int swz(int row, int b) {
  return (row << 9) + (b ^ ((row & 7) << 4) ^ (((row >> 3) & 1) << 5));
}
__device__ __forceinline__ int xswz(int g, int c, int b) {
  return (g << 13) + (c << 5) + (b ^ (((c >> 2) & 1) << 4) ^ (((c >> 3) & 1) << 3));
}
__device__ __forceinline__ int ptbx(int g, int h, int d, int b) {   // b = byte in 32B row
  return (((g*4 + h)*16 + d) << 5) + (b ^ (((h ^ (d >> 2)) & 1) << 4));
}
__device__ __forceinline__ u32 f2bf1(float x) {
  u32 u = __float_as_uint(x);
  return (u + 0x7fffu + ((u >> 16) & 1u)) >> 16;
}
__device__ __forceinline__ u32 pk2(float a, float b) {
  __hip_bfloat162 h2 = __float22bfloat162_rn(make_float2(a, b));
  union { __hip_bfloat162 h; u32 u; } cv; cv.h = h2; return cv.u;
}
__device__ __forceinline__ bf16x8 hbt_read(const SMem& sm, int g, int c, int hi) {
  union { uint2 u2[2]; bf16x8 v; } cv;
  cv.u2[0] = *(const uint2*)(sm.hBT + xswz(g, c, hi*16));
  cv.u2[1] = *(const uint2*)(sm.hBT + xswz(g, c, hi*16 + 8));
  return cv.v;
}

// ---- GEMM x = h @ W via 32x32x16; wave w owns n-tile w (32 cols), both m-halves.
// Waves 0-1 also compute fused att tile (nt=8) for m-half w, then wave-local softmax -> ptb.
template<int KS>
__device__ __forceinline__ void gemm32(SMem& sm, const uint4* __restrict__ wsrc, int t) {
  const int lane = t & 63, w = t >> 6;
  const int l31 = lane & 31, hi = lane >> 5;
  const bool hasAtt = (w < 2);

  f32x16 acc0 = ZERO16, acc1 = ZERO16, accA = ZERO16;

#pragma unroll 4
  for (int ks = 0; ks < KS; ++ks) {
    const uint4 bw = wsrc[(ks*9 + w)*64 + lane];
    uint4 ba;
    if (hasAtt) ba = wsrc[(ks*9 + 8)*64 + lane];
    const bf16x8 a0 = *(const bf16x8*)(sm.hA + swz(l31,      ks*32 + hi*16));
    const bf16x8 a1 = *(const bf16x8*)(sm.hA + swz(32 + l31, ks*32 + hi*16));
    acc0 = MFMA32(a0, *(const bf16x8*)&bw, acc0, 0, 0, 0);
    acc1 = MFMA32(a1, *(const bf16x8*)&bw, acc1, 0, 0, 0);
    if (hasAtt) accA = MFMA32((w == 0) ? a0 : a1, *(const bf16x8*)&ba, accA, 0, 0, 0);
  }

  // X^T epilogue: lane = col c, rows r = (reg&3)+8*(reg>>2)+4*hi
  const int c = w*32 + l31;
#pragma unroll
  for (int mh = 0; mh < 2; ++mh) {
    const f32x16 A = mh ? acc1 : acc0;
#pragma unroll
    for (int grp = 0; grp < 4; ++grp) {
      const int g  = mh*2 + (grp >> 1);
      const int n0 = (grp & 1)*8 + hi*4;
      uint2 o;
      o.x = pk2(A[grp*4+0], A[grp*4+1]);
      o.y = pk2(A[grp*4+2], A[grp*4+3]);
      *(uint2*)(sm.hBT + xswz(g, c, n0*2)) = o;
    }
  }

  if (hasAtt) {
    if (l31 < 8) {
#pragma unroll
      for (int grp = 0; grp < 4; ++grp) {
        const int g  = w*2 + (grp >> 1);
        const int n0 = (grp & 1)*8 + hi*4;
#pragma unroll
        for (int i = 0; i < 4; ++i)
          sm.post.asd[g*16 + n0 + i][l31] = accA[grp*4+i];
      }
    }
    // wave-local softmax (same-wave LDS ops are in-order; no block barrier needed)
    // P-row written via zero-fill + 5 scattered bf16 stores (replaces dense select-chain)
    const int g = w*2 + hi;
    const int h = lane & 3;
#pragma unroll
    for (int dd = 0; dd < 2; ++dd) {
      const int d = ((lane >> 2) & 7) + dd*8;
      const int deg = ADJ_DEG[d];
      const float advl = sm.post.asd[g*16 + d][4 + h];
      float al[5]; int srcs[5];
      float m = -1e30f;
#pragma unroll
      for (int k = 0; k < 5; ++k) {
        srcs[k] = (k < deg) ? ADJ_SRC[d][k] : 99;
        float v = 0.f;
        if (k < deg) {
          v = sm.post.asd[g*16 + srcs[k]][h] + advl;
          v = (v > 0.f) ? v : 0.2f * v;          // leaky_relu 0.2
          m = fmaxf(m, v);
        }
        al[k] = v;
      }
      float ssum = 0.f;
#pragma unroll
      for (int k = 0; k < 5; ++k)
        if (k < deg) { const float e = __expf(al[k] - m); al[k] = e; ssum += e; }
      const float inv = 1.f / ssum;
      char* prow = sm.post.ptb;
      const uint4 z4 = {0u, 0u, 0u, 0u};
      *(uint4*)(prow + ptbx(g, h, d, 0))  = z4;
      *(uint4*)(prow + ptbx(g, h, d, 16)) = z4;
#pragma unroll
      for (int k = 0; k < 5; ++k)
        if (k < deg)
          *(u16*)(prow + ptbx(g, h, d, srcs[k]*2)) = (u16)f2bf1(al[k] * inv);
    }
  }
}

// ---- aggregation: D = X^T @ P_h^T via 32x32x16 ----
template<int MODE>   // 0: concat+bias+relu -> hA; 1: mean heads+nodes + bias -> gr (global)
__device__ __forceinline__ void agg32(SMem& sm, const float* __restrict__ bias, int t,
                                      float* __restrict__ gr, int b0) {
  const int lane = t & 63, w = t >> 6;
  const int l31 = lane & 31, hi = lane >> 5;
  const int g = w >> 1;
  const bf16x8 zero8 = {0,0,0,0,0,0,0,0};

  if (MODE == 0) {
#pragma unroll
    for (int i = 0; i < 4; ++i) {
      const int mt = (w & 1)*4 + i;
      const int h = mt >> 1;                      // head owning this 32-col feature tile
      bf16x8 pb = zero8;
      if (l31 < 16)
        pb = *(const bf16x8*)(sm.post.ptb + ptbx(g, h, l31, hi*16));
      const bf16x8 a = hbt_read(sm, g, mt*32 + l31, hi);
      f32x16 acc = ZERO16;
      acc = MFMA32(a, pb, acc, 0, 0, 0);
      if (l31 < 16) {
        const int row = g*16 + l31;
#pragma unroll
        for (int grp = 0; grp < 4; ++grp) {
          const int cb = mt*32 + grp*8 + hi*4;
          const float4 bv = *(const float4*)(bias + cb);
          uint2 o;
          o.x = pk2(fmaxf(acc[grp*4+0] + bv.x, 0.f), fmaxf(acc[grp*4+1] + bv.y, 0.f));
          o.y = pk2(fmaxf(acc[grp*4+2] + bv.z, 0.f), fmaxf(acc[grp*4+3] + bv.w, 0.f));
          *(uint2*)(sm.hA + swz(row, 2*cb)) = o;
        }
      }
    }
  } else {
    const int mt = w & 1;
    f32x16 acc = ZERO16;
#pragma unroll
    for (int h = 0; h < 4; ++h) {                 // chain heads with per-head P
      bf16x8 pb = zero8;
      if (l31 < 16)
        pb = *(const bf16x8*)(sm.post.ptb + ptbx(g, h, l31, hi*16));
      const bf16x8 a = hbt_read(sm, g, h*64 + mt*32 + l31, hi);
      acc = MFMA32(a, pb, acc, 0, 0, 0);
    }
    // sum over dst nodes (cols = lanes l31 0..15; 16..31 hold zeros) via shuffles,
    // fusing head-mean (x0.25), node-mean (x1/16) and bias -> gr (global) directly.
#pragma unroll
    for (int i = 0; i < 16; ++i) {
      acc[i] += __shfl_xor(acc[i], 1);
      acc[i] += __shfl_xor(acc[i], 2);
      acc[i] += __shfl_xor(acc[i], 4);
      acc[i] += __shfl_xor(acc[i], 8);
    }
    if (l31 < 4) {
      float4 ov;
      if (l31 == 0)      { ov.x = acc[0];  ov.y = acc[1];  ov.z = acc[2];  ov.w = acc[3];  }
      else if (l31 == 1) { ov.x = acc[4];  ov.y = acc[5];  ov.z = acc[6];  ov.w = acc[7];  }
      else if (l31 == 2) { ov.x = acc[8];  ov.y = acc[9];  ov.z = acc[10]; ov.w = acc[11]; }
      else               { ov.x = acc[12]; ov.y = acc[13]; ov.z = acc[14]; ov.w = acc[15]; }
      const int c0 = mt*32 + l31*8 + hi*4;
      const float4 bv = *(const float4*)(bias + c0);
      ov.x = fmaf(1.f/64.f, ov.x, bv.x);
      ov.y = fmaf(1.f/64.f, ov.y, bv.y);
      ov.z = fmaf(1.f/64.f, ov.z, bv.z);
      ov.w = fmaf(1.f/64.f, ov.w, bv.w);
      *(float4*)(gr + (size_t)(b0 + g)*64 + c0) = ov;
    }
  }
}

extern "C" __global__ void __launch_bounds__(512, 4)
gat_main(const float* __restrict__ xg, const float* __restrict__ b_in,
         const float* __restrict__ bias0, const float* __restrict__ bias1,
         const float* __restrict__ bias2,
         const uint4* __restrict__ wq0, const uint4* __restrict__ wq1,
         const uint4* __restrict__ wq2, const uint4* __restrict__ winq,
         float* __restrict__ gr, int Btot)
{
  __shared__ SMem sm;
  const int t = threadIdx.x;
  const int b0 = blockIdx.x * GPB;
  if (b0 >= Btot) return;
  const int lane = t & 63, w = t >> 6;
  const int l31 = lane & 31, hi = lane >> 5;

  // ---- in-proj via MFMA: x loaded straight to B-fragments (waves 0-3) ----
  if (w < 4) {
    const int mtC = w & 1, ntN = w >> 1;
    const int gg = ntN*2 + (l31 >> 4), node = l31 & 15;
    float xv[8];
#pragma unroll
    for (int j = 0; j < 8; ++j)
      xv[j] = xg[(size_t)(b0 + gg)*256 + (hi*8 + j)*16 + node];
    union { u32 uu[4]; bf16x8 v; } bcv;
#pragma unroll
    for (int j = 0; j < 4; ++j) bcv.uu[j] = pk2(xv[2*j], xv[2*j+1]);
    const uint4 aw4 = winq[mtC*64 + lane];
    f32x16 acc = ZERO16;
    acc = MFMA32(*(const bf16x8*)&aw4, bcv.v, acc, 0, 0, 0);
    const int row = ntN*32 + l31;
#pragma unroll
    for (int grp = 0; grp < 4; ++grp) {
      const int cb = mtC*32 + grp*8 + hi*4;
      const float4 bv = *(const float4*)(b_in + cb);
      uint2 o;
      o.x = pk2(fmaxf(acc[grp*4+0] + bv.x, 0.f), fmaxf(acc[grp*4+1] + bv.y, 0.f));
      o.y = pk2(fmaxf(acc[grp*4+2] + bv.z, 0.f), fmaxf(acc[grp*4+3] + bv.w, 0.f));
      *(uint2*)(sm.hA + swz(row, 2*cb)) = o;
    }
  }
  __syncthreads();

  // ---- GAT layers ----
  gemm32<4>(sm, wq0, t);            __syncthreads();
  agg32<0>(sm, bias0, t, gr, b0);   __syncthreads();

  gemm32<16>(sm, wq1, t);           __syncthreads();
  agg32<0>(sm, bias1, t, gr, b0);   __syncthreads();

  gemm32<16>(sm, wq2, t);           __syncthreads();
  agg32<1>(sm, bias2, t, gr, b0);   // writes gr to global; block retires
}

// ---- MLP kernel: 4 graphs/block, weights from L2, ~2.5 KB LDS -> high occupancy ----
extern "C" __global__ void __launch_bounds__(512)
mlp_kernel(const float* __restrict__ mw1, const float* __restrict__ mb1,
           const float* __restrict__ g1, const float* __restrict__ be1,
           const u32* __restrict__ mwb2, const float* __restrict__ mb2,
           const float* __restrict__ g2, const float* __restrict__ be2,
           const float* __restrict__ gr, float* __restrict__ out, int Btot)
{
  __shared__ float grs[4][64];
  __shared__ float z1[4][128];
  __shared__ float red[2][8][2];
  const int t = threadIdx.x;
  const int b0 = blockIdx.x * 4;
  if (b0 >= Btot) return;
  if (t < 256) grs[t >> 6][t & 63] = gr[(size_t)b0*64 + t];
  __syncthreads();

  const int mg = t >> 7, o = t & 127, w = t >> 6, lane = t & 63;

  // MLP1 [64]->[128]
  float a1v = mb1[o];
#pragma unroll 8
  for (int k = 0; k < 64; ++k) a1v = fmaf(grs[mg][k], mw1[k*128 + o], a1v);
  {
    float su = a1v, sq = a1v*a1v;
#pragma unroll
    for (int off = 32; off >= 1; off >>= 1) { su += __shfl_xor(su, off); sq += __shfl_xor(sq, off); }
    if (lane == 0) { red[0][w][0] = su; red[0][w][1] = sq; }
  }
  __syncthreads();
  {
    const float mu = (red[0][2*mg][0] + red[0][2*mg+1][0]) * (1.f/128.f);
    const float mq = (red[0][2*mg][1] + red[0][2*mg+1][1]) * (1.f/128.f);
    const float rstd = rsqrtf(mq - mu*mu + 1e-5f);
    z1[mg][o] = fmaxf((a1v - mu)*rstd*g1[o] + be1[o], 0.f);
  }
  __syncthreads();

  // MLP2 [128]->[256], LN, relu, store
  {
    const float2 bb2 = *(const float2*)(mb2 + 2*o);
    float c0 = bb2.x, c1 = bb2.y;
#pragma unroll 8
    for (int k = 0; k < 128; ++k) {
      const float zk = z1[mg][k];
      const u32 uw = mwb2[k*128 + o];
      c0 = fmaf(zk, __uint_as_float(uw << 16), c0);
      c1 = fmaf(zk, __uint_as_float(uw & 0xffff0000u), c1);
    }
    float su = c0 + c1, sq = c0*c0 + c1*c1;
#pragma unroll
    for (int off = 32; off >= 1; off >>= 1) { su += __shfl_xor(su, off); sq += __shfl_xor(sq, off); }
    if (lane == 0) { red[1][w][0] = su; red[1][w][1] = sq; }
    __syncthreads();
    const float mu = (red[1][2*mg][0] + red[1][2*mg+1][0]) * (1.f/256.f);
    const float mq = (red[1][2*mg][1] + red[1][2*mg+1][1]) * (1.f/256.f);
    const float rstd = rsqrtf(mq - mu*mu + 1e-5f);
    const float2 gg2  = *(const float2*)(g2  + 2*o);
    const float2 bbe2 = *(const float2*)(be2 + 2*o);
    float2 ov;
    ov.x = fmaxf((c0 - mu)*rstd*gg2.x + bbe2.x, 0.f);
    ov.y = fmaxf((c1 - mu)*rstd*gg2.y + bbe2.y, 0.f);
    *(float2*)(out + (size_t)(b0 + mg)*256 + 2*o) = ov;
  }
}

// ---- prepass: 32x32x16 B-fragments (9 n-tiles: 8 cols + fused att) + Win A-frags + mw2 bf16 ----
// u16 layout: wf0 @0 (4*9*512=18432); wf1 @18432 (16*9*512=73728); wf2 @92160 (73728);
//             win @165888 (2*512=1024); mw2 @166912 (32768). total 199680.
__global__ void __launch_bounds__(256)
prep_w(const float* __restrict__ w0, const float* __restrict__ as0, const float* __restrict__ ad0,
       const float* __restrict__ w1, const float* __restrict__ as1, const float* __restrict__ ad1,
       const float* __restrict__ w2, const float* __restrict__ as2, const float* __restrict__ ad2,
       const float* __restrict__ w_in, const float* __restrict__ mw2, u16* __restrict__ wf) {
  const int f = blockIdx.x*256 + threadIdx.x;
  if (f >= 199680) return;
  if (f >= 166912) { wf[f] = (u16)f2bf1(mw2[f - 166912]); return; }
  if (f >= 165888) {
    const int local = f - 165888;
    const int nt = local >> 9, lane = (local >> 3) & 63, j = local & 7;
    wf[f] = (u16)f2bf1(w_in[((lane >> 5)*8 + j)*64 + nt*32 + (lane & 31)]);
    return;
  }
  const float *W, *as_, *ad_; int local;
  if (f < 18432)      { W = w0; as_ = as0; ad_ = ad0; local = f; }
  else if (f < 92160) { W = w1; as_ = as1; ad_ = ad1; local = f - 18432; }
  else                { W = w2; as_ = as2; ad_ = ad2; local = f - 92160; }
  const int ks = local / 4608;
  const int r  = local - ks*4608;
  const int nt = r >> 9;
  const int lane = (r >> 3) & 63;
  const int j = r & 7;
  const int k = ks*16 + (lane >> 5)*8 + j;
  const int col = lane & 31;
  float val;
  if (nt < 8) {
    val = W[k*256 + nt*32 + col];
  } else if (col < 8) {
    const int h = col & 3;
    const float* av = (col < 4) ? as_ : ad_;
    float s = 0.f;
    for (int c = 0; c < 64; ++c) s = fmaf(W[k*256 + h*64 + c], av[h*64 + c], s);
    val = s;
  } else {
    val = 0.f;
  }
  wf[f] = (u16)f2bf1(val);
}

extern "C" void kernel_launch(void* const* d_in, const int* in_sizes, int n_in,
                              void* d_out, int out_size, void* d_ws, size_t ws_size,
                              hipStream_t stream) {
  (void)n_in; (void)out_size; (void)ws_size;
  const float* xg   = (const float*)d_in[0];
  const float* w_in = (const float*)d_in[1];
  const float* b_in = (const float*)d_in[2];
  const float* w0   = (const float*)d_in[3];
  const float* as0  = (const float*)d_in[4];
  const float* ad0  = (const float*)d_in[5];
  const float* bi0  = (const float*)d_in[6];
  const float* w1   = (const float*)d_in[7];
  const float* as1  = (const float*)d_in[8];
  const float* ad1  = (const float*)d_in[9];
  const float* bi1  = (const float*)d_in[10];
  const float* w2   = (const float*)d_in[11];
  const float* as2  = (const float*)d_in[12];
  const float* ad2  = (const float*)d_in[13];
  const float* bi2  = (const float*)d_in[14];
  const float* mw1  = (const float*)d_in[15];
  const float* mb1  = (const float*)d_in[16];
  const float* g1   = (const float*)d_in[17];
  const float* be1  = (const float*)d_in[18];
  const float* mw2  = (const float*)d_in[19];
  const float* mb2  = (const float*)d_in[20];
  const float* g2   = (const float*)d_in[21];
  const float* be2  = (const float*)d_in[22];
  float* out = (float*)d_out;

  const int Btot = in_sizes[0] / 256;               // 8192
  u16* wf = (u16*)d_ws;                             // 199680 u16 = 399360 B
  const uint4* wq0  = (const uint4*)wf;
  const uint4* wq1  = (const uint4*)(wf + 18432);
  const uint4* wq2  = (const uint4*)(wf + 92160);
  const uint4* winq = (const uint4*)(wf + 165888);
  const u32*   mwb2 = (const u32*)(wf + 166912);
  float* gr = (float*)((char*)d_ws + 401408);       // [Btot][64] fp32 = 2 MB

  hipLaunchKernelGGL(prep_w, dim3(780), dim3(256), 0, stream,
                     w0, as0, ad0, w1, as1, ad1, w2, as2, ad2, w_in, mw2, wf);

  const int nblocks = (Btot + GPB - 1) / GPB;       // 2048
  hipLaunchKernelGGL(gat_main, dim3(nblocks), dim3(512), 0, stream,
                     xg, b_in, bi0, bi1, bi2, wq0, wq1, wq2, winq, gr, Btot);

  hipLaunchKernelGGL(mlp_kernel, dim3((Btot + 3) / 4), dim3(512), 0, stream,
                     mw1, mb1, g1, be1, mwb2, mb2, g2, be2, gr, out, Btot);
}